// Round 6
// baseline (2416.804 us; speedup 1.0000x reference)
//
#include <hip/hip_runtime.h>

// 2-layer LSTM encoder, B=128, T=1024, F=1, HID=128, EMB=64.
// R6 = R4 skeleton (512 thr, 8 waves, heavy waves 0-3 do L1+L2, light 4-7 do
// L1 only; superstep s = L1(s) || L2(s-1); ONE barrier/superstep) plus:
//  - zacc C-operand: no per-step accumulator init (bias/x*w post-added in ew)
//  - all LDS loads clustered at barrier release; B-MFMA issued before A-ew
//    so its issue hides A's acc-read + transcendental latency
//  - 2-step unroll with compile-time ping-pong slots
// Slot audit (p = s&1): A reads H1[p^1], writes H1[p]; B(s-1) reads H2[p],
// writes H2[p^1]. Every cross-step RAW/WAR spans the end-of-step barrier.

#define TB   1024
#define HID1 128
#define EMB2 64

typedef _Float16 f16x8 __attribute__((ext_vector_type(8)));
typedef float    f32x4 __attribute__((ext_vector_type(4)));

#define MFMA16(a,b,c) __builtin_amdgcn_mfma_f32_16x16x32_f16((a),(b),(c),0,0,0)

static __device__ __forceinline__ float fast_exp2(float x){
#if __has_builtin(__builtin_amdgcn_exp2f)
  return __builtin_amdgcn_exp2f(x);
#else
  return __exp2f(x);
#endif
}
static __device__ __forceinline__ float fast_rcp(float x){
#if __has_builtin(__builtin_amdgcn_rcpf)
  return __builtin_amdgcn_rcpf(x);
#else
  return 1.0f / x;
#endif
}
static __device__ __forceinline__ float sigmoid_f(float x){
  return fast_rcp(1.0f + fast_exp2(-1.44269504088896340736f * x));
}
static __device__ __forceinline__ float tanh_f(float x){
  return 1.0f - 2.0f * fast_rcp(1.0f + fast_exp2(2.88539008177792681472f * x));
}

static __device__ __forceinline__ f16x8 load_frag(const float* p){
  f16x8 r;
  #pragma unroll
  for (int j = 0; j < 8; ++j) r[j] = (_Float16)p[j];
  return r;
}

__launch_bounds__(512, 2)
__global__ void lstm2_kernel(const float* __restrict__ x,
                             const float* __restrict__ w_ih1,
                             const float* __restrict__ w_hh1,
                             const float* __restrict__ b_ih1,
                             const float* __restrict__ b_hh1,
                             const float* __restrict__ w_ih2,
                             const float* __restrict__ w_hh2,
                             const float* __restrict__ b_ih2,
                             const float* __restrict__ b_hh2,
                             float* __restrict__ out)
{
  __shared__ __align__(16) float    xs[TB];
  __shared__ __align__(16) _Float16 H1[2][HID1];  // h1 ping-pong
  __shared__ __align__(16) _Float16 H2[2][EMB2];  // h2 ping-pong

  const int t    = threadIdx.x;   // 0..511
  const int b    = blockIdx.x;    // 0..127
  const int l    = t & 63;        // lane
  const int w    = t >> 6;        // wave 0..7
  const int col  = l & 15;
  const int quad = l >> 4;

  // ---- layer-1 weight B-fragments: wave w owns N-tiles {w,w+8,w+16,w+24} ----
  f16x8 B1[4][4];
  #pragma unroll
  for (int g = 0; g < 4; ++g){
    const int nA = (w + 8*g)*16 + col;
    #pragma unroll
    for (int k = 0; k < 4; ++k)
      B1[g][k] = load_frag(w_hh1 + nA*HID1 + k*32 + quad*8);
  }

  // ---- layer-2 weight B-fragments (waves 0-3): tiles {w,w+4,w+8,w+12} ----
  f16x8 B2i[4][4];   // w_ih2 part, K=128
  f16x8 B2h[4][2];   // w_hh2 part, K=64
  if (w < 4){
    #pragma unroll
    for (int g = 0; g < 4; ++g){
      const int nB = (w + 4*g)*16 + col;
      #pragma unroll
      for (int k = 0; k < 4; ++k)
        B2i[g][k] = load_frag(w_ih2 + nB*HID1 + k*32 + quad*8);
      #pragma unroll
      for (int k = 0; k < 2; ++k)
        B2h[g][k] = load_frag(w_hh2 + nB*EMB2 + k*32 + quad*8);
    }
  }

  // ---- per-lane ew parameters (post-added after MFMA) ----
  const int cA = 16*w + l;             // L1 cell (valid l<16)
  const int cB = 16*w + l;             // L2 cell (valid w<4 && l<16)
  float bias1g[4], wx1g[4], bias2g[4];
  if (l < 16){
    #pragma unroll
    for (int g = 0; g < 4; ++g){
      const int r = g*HID1 + cA;
      bias1g[g] = b_ih1[r] + b_hh1[r];
      wx1g[g]   = w_ih1[r];            // w_ih1 is (512,1)
    }
    if (w < 4){
      #pragma unroll
      for (int g = 0; g < 4; ++g){
        const int r = g*EMB2 + cB;
        bias2g[g] = b_ih2[r] + b_hh2[r];
      }
    }
  }

  // ---- x preload + state init ----
  xs[t]       = x[b * TB + t];
  xs[t + 512] = x[b * TB + t + 512];
  if (t < HID1) { H1[0][t] = (_Float16)0.0f; H1[1][t] = (_Float16)0.0f; }
  else if (t < HID1 + EMB2){
    H2[0][t-HID1] = (_Float16)0.0f; H2[1][t-HID1] = (_Float16)0.0f;
  }
  __syncthreads();

  float c1 = 0.0f, c2 = 0.0f;
  const f32x4 zacc = {0.0f, 0.0f, 0.0f, 0.0f};   // persistent zero C operand

  // One superstep. RA1/WA1 = h1 read/write slot, RA2/WA2 = h2 read/write slot
  // (compile-time constants). S = timestep of phase A; phase B does step S-1.
  // STORE: epilogue-only flag unused here (epilogue is separate).
#define SUPERSTEP(RA1, WA1, RA2, WA2, S)                                \
  {                                                                     \
    /* ---- clustered LDS loads (issued at barrier release) ---- */     \
    const f16x8* pH1_ = (const f16x8*)&H1[(RA1)][0];                    \
    f16x8 a1_[4];                                                       \
    _Pragma("unroll")                                                   \
    for (int k_ = 0; k_ < 4; ++k_) a1_[k_] = pH1_[4*k_ + quad];         \
    f16x8 a2_[2];                                                       \
    if (w < 4){                                                         \
      const f16x8* pH2_ = (const f16x8*)&H2[(RA2)][0];                  \
      _Pragma("unroll")                                                 \
      for (int k_ = 0; k_ < 2; ++k_) a2_[k_] = pH2_[4*k_ + quad];       \
    }                                                                   \
    const float xt_ = xs[(S)];                                          \
    /* ---- A MFMA: depth-2 chains from persistent zero ---- */         \
    f32x4 aA_[4], aB_[4];                                               \
    _Pragma("unroll")                                                   \
    for (int g_ = 0; g_ < 4; ++g_){                                     \
      aA_[g_] = MFMA16(a1_[0], B1[g_][0], zacc);                        \
      aB_[g_] = MFMA16(a1_[2], B1[g_][2], zacc);                        \
    }                                                                   \
    _Pragma("unroll")                                                   \
    for (int g_ = 0; g_ < 4; ++g_){                                     \
      aA_[g_] = MFMA16(a1_[1], B1[g_][1], aA_[g_]);                     \
      aB_[g_] = MFMA16(a1_[3], B1[g_][3], aB_[g_]);                     \
    }                                                                   \
    /* ---- B MFMA (independent of A results; hides A latency) ---- */  \
    f32x4 bA_[4], bB_[4];                                               \
    if (w < 4){                                                         \
      _Pragma("unroll")                                                 \
      for (int g_ = 0; g_ < 4; ++g_){                                   \
        bA_[g_] = MFMA16(a1_[0], B2i[g_][0], zacc);                     \
        bB_[g_] = MFMA16(a1_[2], B2i[g_][2], zacc);                     \
      }                                                                 \
      _Pragma("unroll")                                                 \
      for (int g_ = 0; g_ < 4; ++g_){                                   \
        bA_[g_] = MFMA16(a1_[1], B2i[g_][1], bA_[g_]);                  \
        bB_[g_] = MFMA16(a1_[3], B2i[g_][3], bB_[g_]);                  \
      }                                                                 \
      _Pragma("unroll")                                                 \
      for (int g_ = 0; g_ < 4; ++g_){                                   \
        bA_[g_] = MFMA16(a2_[0], B2h[g_][0], bA_[g_]);                  \
        bB_[g_] = MFMA16(a2_[1], B2h[g_][1], bB_[g_]);                  \
      }                                                                 \
    }                                                                   \
    /* ---- A elementwise (lanes<16) ---- */                            \
    if (l < 16){                                                        \
      float g4_[4];                                                     \
      _Pragma("unroll")                                                 \
      for (int g_ = 0; g_ < 4; ++g_)                                    \
        g4_[g_] = aA_[g_][0] + aB_[g_][0]                               \
                + __builtin_fmaf(xt_, wx1g[g_], bias1g[g_]);            \
      c1 = sigmoid_f(g4_[1]) * c1 + sigmoid_f(g4_[0]) * tanh_f(g4_[2]); \
      float h_ = sigmoid_f(g4_[3]) * tanh_f(c1);                        \
      H1[(WA1)][cA] = (_Float16)h_;                                     \
    }                                                                   \
    /* ---- B elementwise (heavy waves, lanes<16) ---- */               \
    if (w < 4 && l < 16){                                               \
      float g4_[4];                                                     \
      _Pragma("unroll")                                                 \
      for (int g_ = 0; g_ < 4; ++g_)                                    \
        g4_[g_] = bA_[g_][0] + bB_[g_][0] + bias2g[g_];                 \
      c2 = sigmoid_f(g4_[1]) * c2 + sigmoid_f(g4_[0]) * tanh_f(g4_[2]); \
      float h_ = sigmoid_f(g4_[3]) * tanh_f(c2);                        \
      H2[(WA2)][cB] = (_Float16)h_;                                     \
    }                                                                   \
    __syncthreads();                                                    \
  }

  // ---- prologue: L1 step 0 only (h1(-1)=zeros in slot 1; no B phase) ----
  {
    const f16x8* pH1_ = (const f16x8*)&H1[1][0];
    f16x8 a1_[4];
    #pragma unroll
    for (int k_ = 0; k_ < 4; ++k_) a1_[k_] = pH1_[4*k_ + quad];
    const float xt_ = xs[0];
    f32x4 aA_[4], aB_[4];
    #pragma unroll
    for (int g_ = 0; g_ < 4; ++g_){
      aA_[g_] = MFMA16(a1_[0], B1[g_][0], zacc);
      aB_[g_] = MFMA16(a1_[2], B1[g_][2], zacc);
    }
    #pragma unroll
    for (int g_ = 0; g_ < 4; ++g_){
      aA_[g_] = MFMA16(a1_[1], B1[g_][1], aA_[g_]);
      aB_[g_] = MFMA16(a1_[3], B1[g_][3], aB_[g_]);
    }
    if (l < 16){
      float g4_[4];
      #pragma unroll
      for (int g_ = 0; g_ < 4; ++g_)
        g4_[g_] = aA_[g_][0] + aB_[g_][0]
                + __builtin_fmaf(xt_, wx1g[g_], bias1g[g_]);
      c1 = sigmoid_f(g4_[1]) * c1 + sigmoid_f(g4_[0]) * tanh_f(g4_[2]);
      float h_ = sigmoid_f(g4_[3]) * tanh_f(c1);
      H1[0][cA] = (_Float16)h_;
    }
    __syncthreads();
  }

  // ---- main loop: 511 pairs covering s=1..1022 (odd, even) ----
  #pragma unroll 1
  for (int s = 1; s < TB - 1; s += 2){
    SUPERSTEP(0, 1, 1, 0, s)       // odd  s: A reads H1[0] writes H1[1]; B reads H2[1] writes H2[0]
    SUPERSTEP(1, 0, 0, 1, s + 1)   // even s: A reads H1[1] writes H1[0]; B reads H2[0] writes H2[1]
  }

  // ---- tail superstep s=1023 (odd): A(1023), B(1022) ----
  SUPERSTEP(0, 1, 1, 0, TB - 1)

  // ---- epilogue: B(1023) -> out. h1(1023) in H1[1], h2(1022) in H2[0] ----
  if (w < 4){
    const f16x8* pH1_ = (const f16x8*)&H1[1][0];
    f16x8 a1_[4];
    #pragma unroll
    for (int k_ = 0; k_ < 4; ++k_) a1_[k_] = pH1_[4*k_ + quad];
    const f16x8* pH2_ = (const f16x8*)&H2[0][0];
    f16x8 a2_[2];
    #pragma unroll
    for (int k_ = 0; k_ < 2; ++k_) a2_[k_] = pH2_[4*k_ + quad];
    f32x4 bA_[4], bB_[4];
    #pragma unroll
    for (int g_ = 0; g_ < 4; ++g_){
      bA_[g_] = MFMA16(a1_[0], B2i[g_][0], zacc);
      bB_[g_] = MFMA16(a1_[2], B2i[g_][2], zacc);
    }
    #pragma unroll
    for (int g_ = 0; g_ < 4; ++g_){
      bA_[g_] = MFMA16(a1_[1], B2i[g_][1], bA_[g_]);
      bB_[g_] = MFMA16(a1_[3], B2i[g_][3], bB_[g_]);
    }
    #pragma unroll
    for (int g_ = 0; g_ < 4; ++g_){
      bA_[g_] = MFMA16(a2_[0], B2h[g_][0], bA_[g_]);
      bB_[g_] = MFMA16(a2_[1], B2h[g_][1], bB_[g_]);
    }
    if (l < 16){
      float g4_[4];
      #pragma unroll
      for (int g_ = 0; g_ < 4; ++g_)
        g4_[g_] = bA_[g_][0] + bB_[g_][0] + bias2g[g_];
      c2 = sigmoid_f(g4_[1]) * c2 + sigmoid_f(g4_[0]) * tanh_f(g4_[2]);
      float h_ = sigmoid_f(g4_[3]) * tanh_f(c2);
      out[b * EMB2 + cB] = h_;
    }
  }

#undef SUPERSTEP
}

extern "C" void kernel_launch(void* const* d_in, const int* in_sizes, int n_in,
                              void* d_out, int out_size, void* d_ws, size_t ws_size,
                              hipStream_t stream) {
  lstm2_kernel<<<dim3(128), dim3(512), 0, stream>>>(
      (const float*)d_in[0],   // x
      (const float*)d_in[1],   // w_ih1
      (const float*)d_in[2],   // w_hh1
      (const float*)d_in[3],   // b_ih1
      (const float*)d_in[4],   // b_hh1
      (const float*)d_in[5],   // w_ih2
      (const float*)d_in[6],   // w_hh2
      (const float*)d_in[7],   // b_ih2
      (const float*)d_in[8],   // b_hh2
      (float*)d_out);
}

// Round 8
// 806.290 us; speedup vs baseline: 2.9974x; 2.9974x over previous
//
#include <hip/hip_runtime.h>

// 2-layer LSTM encoder, B=128, T=1024, F=1, HID=128, EMB=64.
// R8 = R7 with the epilogue H2 slot fix (h2(m) lives in slot m&1; epilogue
// needs h2(1022) -> H2[0], R7 wrongly read H2[1]).
// Structure: R4 skeleton (512 thr, 8 waves; heavy waves 0-3 do L1+L2, light
// 4-7 L1 only; superstep s = L1(s) || L2(s-1); ONE barrier/superstep) plus:
//   - a2 (h2) LDS loads issued at barrier release together with a1
//   - B's w_ih2 MFMA block (a1-only) issued BEFORE A's elementwise, so its
//     issue+latency drains under A's transcendental chain
//   - B's w_hh2 MFMA stays after A-ew (accA and accB never both peak-live)
// Heavy-wave live set ~242 unified regs <= 250 cap for 2 waves/SIMD
// (R5/R6 lesson: >256 -> scratch spill, WRITE_SIZE explodes).

#define TB   1024
#define HID1 128
#define EMB2 64

typedef _Float16 f16x8 __attribute__((ext_vector_type(8)));
typedef float    f32x4 __attribute__((ext_vector_type(4)));

#define MFMA16(a,b,c) __builtin_amdgcn_mfma_f32_16x16x32_f16((a),(b),(c),0,0,0)

static __device__ __forceinline__ float fast_exp2(float x){
#if __has_builtin(__builtin_amdgcn_exp2f)
  return __builtin_amdgcn_exp2f(x);
#else
  return __exp2f(x);
#endif
}
static __device__ __forceinline__ float fast_rcp(float x){
#if __has_builtin(__builtin_amdgcn_rcpf)
  return __builtin_amdgcn_rcpf(x);
#else
  return 1.0f / x;
#endif
}
static __device__ __forceinline__ float sigmoid_f(float x){
  return fast_rcp(1.0f + fast_exp2(-1.44269504088896340736f * x));
}
static __device__ __forceinline__ float tanh_f(float x){
  return 1.0f - 2.0f * fast_rcp(1.0f + fast_exp2(2.88539008177792681472f * x));
}

static __device__ __forceinline__ f16x8 load_frag(const float* p){
  f16x8 r;
  #pragma unroll
  for (int j = 0; j < 8; ++j) r[j] = (_Float16)p[j];
  return r;
}

__launch_bounds__(512, 2)
__global__ void lstm2_kernel(const float* __restrict__ x,
                             const float* __restrict__ w_ih1,
                             const float* __restrict__ w_hh1,
                             const float* __restrict__ b_ih1,
                             const float* __restrict__ b_hh1,
                             const float* __restrict__ w_ih2,
                             const float* __restrict__ w_hh2,
                             const float* __restrict__ b_ih2,
                             const float* __restrict__ b_hh2,
                             float* __restrict__ out)
{
  __shared__ __align__(16) float    xs[TB];
  __shared__ __align__(16) _Float16 H1[2][HID1];  // h1 ping-pong
  __shared__ __align__(16) _Float16 H2[2][EMB2];  // h2 ping-pong

  const int t    = threadIdx.x;   // 0..511
  const int b    = blockIdx.x;    // 0..127
  const int l    = t & 63;        // lane
  const int w    = t >> 6;        // wave 0..7
  const int col  = l & 15;
  const int quad = l >> 4;

  // ---- layer-1 weight B-fragments: wave w owns N-tiles {w,w+8,w+16,w+24} ----
  f16x8 B1[4][4];
  float biasA[4], wxA[4];
  #pragma unroll
  for (int g = 0; g < 4; ++g){
    const int nA = (w + 8*g)*16 + col;
    biasA[g] = b_ih1[nA] + b_hh1[nA];
    wxA[g]   = w_ih1[nA];                       // w_ih1 is (512,1)
    #pragma unroll
    for (int k = 0; k < 4; ++k)
      B1[g][k] = load_frag(w_hh1 + nA*HID1 + k*32 + quad*8);
  }

  // ---- layer-2 weight B-fragments (waves 0-3): tiles {w,w+4,w+8,w+12} ----
  f16x8 B2i[4][4];   // w_ih2 part, K=128
  f16x8 B2h[4][2];   // w_hh2 part, K=64
  float biasB[4];
  if (w < 4){
    #pragma unroll
    for (int g = 0; g < 4; ++g){
      const int nB = (w + 4*g)*16 + col;
      biasB[g] = b_ih2[nB] + b_hh2[nB];
      #pragma unroll
      for (int k = 0; k < 4; ++k)
        B2i[g][k] = load_frag(w_ih2 + nB*HID1 + k*32 + quad*8);
      #pragma unroll
      for (int k = 0; k < 2; ++k)
        B2h[g][k] = load_frag(w_hh2 + nB*EMB2 + k*32 + quad*8);
    }
  }

  // ---- x preload + state init ----
  xs[t]       = x[b * TB + t];
  xs[t + 512] = x[b * TB + t + 512];
  if (t < HID1) { H1[0][t] = (_Float16)0.0f; H1[1][t] = (_Float16)0.0f; }
  else if (t < HID1 + EMB2){
    H2[0][t-HID1] = (_Float16)0.0f; H2[1][t-HID1] = (_Float16)0.0f;
  }
  __syncthreads();

  float c1 = 0.0f, c2 = 0.0f;
  const int cellA = 16*w + l;          // valid when l<16
  const int cellB = 16*w + l;          // valid when w<4 && l<16

  // ---- prologue: L1 step 0 (h1(-1) = zeros in slot 1) ----
  {
    const f16x8* pA = (const f16x8*)&H1[1][0];
    f16x8 a1[4];
    #pragma unroll
    for (int k = 0; k < 4; ++k) a1[k] = pA[4*k + quad];
    const float xt = xs[0];
    f32x4 acc[4];
    #pragma unroll
    for (int g = 0; g < 4; ++g){
      const float pre = __builtin_fmaf(xt, wxA[g], biasA[g]);
      acc[g] = (f32x4){pre, 0.0f, 0.0f, 0.0f};
    }
    #pragma unroll
    for (int k = 0; k < 4; ++k)
      #pragma unroll
      for (int g = 0; g < 4; ++g)
        acc[g] = MFMA16(a1[k], B1[g][k], acc[g]);
    if (l < 16){
      float gi = acc[0][0], gf = acc[1][0], gg = acc[2][0], go = acc[3][0];
      c1 = sigmoid_f(gf) * c1 + sigmoid_f(gi) * tanh_f(gg);
      float h = sigmoid_f(go) * tanh_f(c1);
      H1[0][cellA] = (_Float16)h;
    }
    __syncthreads();
  }

  // ---- main pipelined loop: superstep s = L1(s) || L2(s-1), one barrier ----
  #pragma unroll 1
  for (int s = 1; s < TB; ++s){
    const int ra1 = (s + 1) & 1;       // h1(s-1) slot
    const int wa1 = s & 1;             // h1(s)   slot
    const int ra2 = s & 1;             // h2(s-2) slot  ((s-2)&1 == s&1)
    const int wa2 = (s + 1) & 1;       // h2(s-1) slot  ((s-1)&1 == (s+1)&1)

    // ---- clustered LDS loads at barrier release ----
    const f16x8* pA1 = (const f16x8*)&H1[ra1][0];
    f16x8 a1[4];
    #pragma unroll
    for (int k = 0; k < 4; ++k) a1[k] = pA1[4*k + quad];
    f16x8 a2[2];
    if (w < 4){
      const f16x8* pA2 = (const f16x8*)&H2[ra2][0];
      #pragma unroll
      for (int k = 0; k < 2; ++k) a2[k] = pA2[4*k + quad];
    }
    const float xt = xs[s];

    // ---- A MFMA: single chain depth 4 per gate (R4 style) ----
    f32x4 acc[4];
    #pragma unroll
    for (int g = 0; g < 4; ++g){
      const float pre = __builtin_fmaf(xt, wxA[g], biasA[g]);
      acc[g] = (f32x4){pre, 0.0f, 0.0f, 0.0f};
    }
    #pragma unroll
    for (int k = 0; k < 4; ++k)
      #pragma unroll
      for (int g = 0; g < 4; ++g)
        acc[g] = MFMA16(a1[k], B1[g][k], acc[g]);

    // ---- B MFMA, w_ih2 part (a1-only) — issued before A-ew so its
    //      issue+latency hides under A's transcendental chain ----
    f32x4 acc2[4];
    if (w < 4){
      #pragma unroll
      for (int g = 0; g < 4; ++g)
        acc2[g] = (f32x4){biasB[g], 0.0f, 0.0f, 0.0f};
      #pragma unroll
      for (int k = 0; k < 4; ++k)
        #pragma unroll
        for (int g = 0; g < 4; ++g)
          acc2[g] = MFMA16(a1[k], B2i[g][k], acc2[g]);
    }

    // ---- A elementwise (lanes<16): accA dies here ----
    if (l < 16){
      float gi = acc[0][0], gf = acc[1][0], gg = acc[2][0], go = acc[3][0];
      c1 = sigmoid_f(gf) * c1 + sigmoid_f(gi) * tanh_f(gg);
      float h = sigmoid_f(go) * tanh_f(c1);
      H1[wa1][cellA] = (_Float16)h;
    }

    // ---- B MFMA, w_hh2 part (a2 preloaded — no stall) + B ew ----
    if (w < 4){
      #pragma unroll
      for (int k = 0; k < 2; ++k)
        #pragma unroll
        for (int g = 0; g < 4; ++g)
          acc2[g] = MFMA16(a2[k], B2h[g][k], acc2[g]);
      if (l < 16){
        float gi = acc2[0][0], gf = acc2[1][0], gg = acc2[2][0], go = acc2[3][0];
        c2 = sigmoid_f(gf) * c2 + sigmoid_f(gi) * tanh_f(gg);
        float h = sigmoid_f(go) * tanh_f(c2);
        H2[wa2][cellB] = (_Float16)h;
      }
    }
    __syncthreads();
  }

  // ---- epilogue: L2 step TB-1 -> output.
  //      h1(m) lives in slot m&1  -> h1(1023) in H1[1]
  //      h2(m) lives in slot m&1  -> h2(1022) in H2[0]   (R7 bug: read H2[1])
  if (w < 4){
    const f16x8* pA1 = (const f16x8*)&H1[1][0];
    f16x8 a1[4];
    #pragma unroll
    for (int k = 0; k < 4; ++k) a1[k] = pA1[4*k + quad];
    const f16x8* pA2 = (const f16x8*)&H2[0][0];
    f16x8 a2[2];
    #pragma unroll
    for (int k = 0; k < 2; ++k) a2[k] = pA2[4*k + quad];
    f32x4 acc2[4];
    #pragma unroll
    for (int g = 0; g < 4; ++g)
      acc2[g] = (f32x4){biasB[g], 0.0f, 0.0f, 0.0f};
    #pragma unroll
    for (int k = 0; k < 4; ++k)
      #pragma unroll
      for (int g = 0; g < 4; ++g)
        acc2[g] = MFMA16(a1[k], B2i[g][k], acc2[g]);
    #pragma unroll
    for (int k = 0; k < 2; ++k)
      #pragma unroll
      for (int g = 0; g < 4; ++g)
        acc2[g] = MFMA16(a2[k], B2h[g][k], acc2[g]);
    if (l < 16){
      float gi = acc2[0][0], gf = acc2[1][0], gg = acc2[2][0], go = acc2[3][0];
      c2 = sigmoid_f(gf) * c2 + sigmoid_f(gi) * tanh_f(gg);
      float h = sigmoid_f(go) * tanh_f(c2);
      out[b * EMB2 + cellB] = h;
    }
  }
}

extern "C" void kernel_launch(void* const* d_in, const int* in_sizes, int n_in,
                              void* d_out, int out_size, void* d_ws, size_t ws_size,
                              hipStream_t stream) {
  lstm2_kernel<<<dim3(128), dim3(512), 0, stream>>>(
      (const float*)d_in[0],   // x
      (const float*)d_in[1],   // w_ih1
      (const float*)d_in[2],   // w_hh1
      (const float*)d_in[3],   // b_ih1
      (const float*)d_in[4],   // b_hh1
      (const float*)d_in[5],   // w_ih2
      (const float*)d_in[6],   // w_hh2
      (const float*)d_in[7],   // b_ih2
      (const float*)d_in[8],   // b_hh2
      (float*)d_out);
}

// Round 9
// 756.670 us; speedup vs baseline: 3.1940x; 1.0656x over previous
//
#include <hip/hip_runtime.h>

// 2-layer LSTM encoder, B=128, T=1024, F=1, HID=128, EMB=64.
// R9 = R4 ordering (B-MFMA strictly after A-ew; no acc sets co-live) +
//   - a2 (h2) LDS load clustered at barrier release (+8 regs only)
//   - split accumulator chains: A = 2x depth-2 per gate, B = 2x depth-3
//     (ih k0,k1 + hh k0 | ih k2,k3 + hh k1), combined in elementwise
//   - persistent zero C-operand (zacc) for all chain heads; bias + x*w
//     post-added in elementwise (no per-step acc init movs)
// Peak live set ~235 arch VGPRs <= ~240 cap for 2 waves/SIMD
// (R5/R6/R8 lesson: ordering sets peak liveness; >~250 -> scratch spill).
// Slot audit (verified in R8): h1(m) -> H1[m&1]; h2(m) -> H2[m&1];
// epilogue reads h1(1023)=H1[1], h2(1022)=H2[0].

#define TB   1024
#define HID1 128
#define EMB2 64

typedef _Float16 f16x8 __attribute__((ext_vector_type(8)));
typedef float    f32x4 __attribute__((ext_vector_type(4)));

#define MFMA16(a,b,c) __builtin_amdgcn_mfma_f32_16x16x32_f16((a),(b),(c),0,0,0)

static __device__ __forceinline__ float fast_exp2(float x){
#if __has_builtin(__builtin_amdgcn_exp2f)
  return __builtin_amdgcn_exp2f(x);
#else
  return __exp2f(x);
#endif
}
static __device__ __forceinline__ float fast_rcp(float x){
#if __has_builtin(__builtin_amdgcn_rcpf)
  return __builtin_amdgcn_rcpf(x);
#else
  return 1.0f / x;
#endif
}
static __device__ __forceinline__ float sigmoid_f(float x){
  return fast_rcp(1.0f + fast_exp2(-1.44269504088896340736f * x));
}
static __device__ __forceinline__ float tanh_f(float x){
  return 1.0f - 2.0f * fast_rcp(1.0f + fast_exp2(2.88539008177792681472f * x));
}

static __device__ __forceinline__ f16x8 load_frag(const float* p){
  f16x8 r;
  #pragma unroll
  for (int j = 0; j < 8; ++j) r[j] = (_Float16)p[j];
  return r;
}

__launch_bounds__(512, 2)
__global__ void lstm2_kernel(const float* __restrict__ x,
                             const float* __restrict__ w_ih1,
                             const float* __restrict__ w_hh1,
                             const float* __restrict__ b_ih1,
                             const float* __restrict__ b_hh1,
                             const float* __restrict__ w_ih2,
                             const float* __restrict__ w_hh2,
                             const float* __restrict__ b_ih2,
                             const float* __restrict__ b_hh2,
                             float* __restrict__ out)
{
  __shared__ __align__(16) float    xs[TB];
  __shared__ __align__(16) _Float16 H1[2][HID1];  // h1 ping-pong
  __shared__ __align__(16) _Float16 H2[2][EMB2];  // h2 ping-pong

  const int t    = threadIdx.x;   // 0..511
  const int b    = blockIdx.x;    // 0..127
  const int l    = t & 63;        // lane
  const int w    = t >> 6;        // wave 0..7
  const int col  = l & 15;
  const int quad = l >> 4;

  // ---- layer-1 weight B-fragments: wave w owns N-tiles {w,w+8,w+16,w+24} ----
  f16x8 B1[4][4];
  float biasA[4], wxA[4];
  #pragma unroll
  for (int g = 0; g < 4; ++g){
    const int nA = (w + 8*g)*16 + col;
    biasA[g] = b_ih1[nA] + b_hh1[nA];
    wxA[g]   = w_ih1[nA];                       // w_ih1 is (512,1)
    #pragma unroll
    for (int k = 0; k < 4; ++k)
      B1[g][k] = load_frag(w_hh1 + nA*HID1 + k*32 + quad*8);
  }

  // ---- layer-2 weight B-fragments (waves 0-3): tiles {w,w+4,w+8,w+12} ----
  f16x8 B2i[4][4];   // w_ih2 part, K=128
  f16x8 B2h[4][2];   // w_hh2 part, K=64
  float biasB[4];
  if (w < 4){
    #pragma unroll
    for (int g = 0; g < 4; ++g){
      const int nB = (w + 4*g)*16 + col;
      biasB[g] = b_ih2[nB] + b_hh2[nB];
      #pragma unroll
      for (int k = 0; k < 4; ++k)
        B2i[g][k] = load_frag(w_ih2 + nB*HID1 + k*32 + quad*8);
      #pragma unroll
      for (int k = 0; k < 2; ++k)
        B2h[g][k] = load_frag(w_hh2 + nB*EMB2 + k*32 + quad*8);
    }
  }

  // ---- x preload + state init ----
  xs[t]       = x[b * TB + t];
  xs[t + 512] = x[b * TB + t + 512];
  if (t < HID1) { H1[0][t] = (_Float16)0.0f; H1[1][t] = (_Float16)0.0f; }
  else if (t < HID1 + EMB2){
    H2[0][t-HID1] = (_Float16)0.0f; H2[1][t-HID1] = (_Float16)0.0f;
  }
  __syncthreads();

  float c1 = 0.0f, c2 = 0.0f;
  const int cellA = 16*w + l;          // valid when l<16
  const int cellB = 16*w + l;          // valid when w<4 && l<16
  const f32x4 zacc = {0.0f, 0.0f, 0.0f, 0.0f};   // persistent zero C operand

  // ---- prologue: L1 step 0 (h1(-1) = zeros in slot 1) ----
  {
    const f16x8* pA = (const f16x8*)&H1[1][0];
    f16x8 a1[4];
    #pragma unroll
    for (int k = 0; k < 4; ++k) a1[k] = pA[4*k + quad];
    const float xt = xs[0];
    f32x4 aLo[4], aHi[4];
    #pragma unroll
    for (int g = 0; g < 4; ++g){
      aLo[g] = MFMA16(a1[0], B1[g][0], zacc);
      aHi[g] = MFMA16(a1[2], B1[g][2], zacc);
    }
    #pragma unroll
    for (int g = 0; g < 4; ++g){
      aLo[g] = MFMA16(a1[1], B1[g][1], aLo[g]);
      aHi[g] = MFMA16(a1[3], B1[g][3], aHi[g]);
    }
    if (l < 16){
      float g4[4];
      #pragma unroll
      for (int g = 0; g < 4; ++g)
        g4[g] = aLo[g][0] + aHi[g][0] + __builtin_fmaf(xt, wxA[g], biasA[g]);
      c1 = sigmoid_f(g4[1]) * c1 + sigmoid_f(g4[0]) * tanh_f(g4[2]);
      float h = sigmoid_f(g4[3]) * tanh_f(c1);
      H1[0][cellA] = (_Float16)h;
    }
    __syncthreads();
  }

  // ---- main pipelined loop: superstep s = L1(s) || L2(s-1), one barrier ----
  #pragma unroll 1
  for (int s = 1; s < TB; ++s){
    const int ra1 = (s + 1) & 1;       // h1(s-1) slot
    const int wa1 = s & 1;             // h1(s)   slot
    const int ra2 = s & 1;             // h2(s-2) slot
    const int wa2 = (s + 1) & 1;       // h2(s-1) slot

    // ---- clustered LDS loads at barrier release ----
    const f16x8* pA1 = (const f16x8*)&H1[ra1][0];
    f16x8 a1[4];
    #pragma unroll
    for (int k = 0; k < 4; ++k) a1[k] = pA1[4*k + quad];
    f16x8 a2[2];
    if (w < 4){
      const f16x8* pA2 = (const f16x8*)&H2[ra2][0];
      #pragma unroll
      for (int k = 0; k < 2; ++k) a2[k] = pA2[4*k + quad];
    }
    const float xt = xs[s];

    // ---- A MFMA: 2 chains of depth 2 per gate, heads from zacc ----
    f32x4 aLo[4], aHi[4];
    #pragma unroll
    for (int g = 0; g < 4; ++g){
      aLo[g] = MFMA16(a1[0], B1[g][0], zacc);
      aHi[g] = MFMA16(a1[2], B1[g][2], zacc);
    }
    #pragma unroll
    for (int g = 0; g < 4; ++g){
      aLo[g] = MFMA16(a1[1], B1[g][1], aLo[g]);
      aHi[g] = MFMA16(a1[3], B1[g][3], aHi[g]);
    }

    // ---- A elementwise (lanes<16): accA dies here ----
    if (l < 16){
      float g4[4];
      #pragma unroll
      for (int g = 0; g < 4; ++g)
        g4[g] = aLo[g][0] + aHi[g][0] + __builtin_fmaf(xt, wxA[g], biasA[g]);
      c1 = sigmoid_f(g4[1]) * c1 + sigmoid_f(g4[0]) * tanh_f(g4[2]);
      float h = sigmoid_f(g4[3]) * tanh_f(c1);
      H1[wa1][cellA] = (_Float16)h;
    }

    // ---- B MFMA (after A-ew, R4 ordering): 2 chains of depth 3 per gate ----
    if (w < 4){
      f32x4 bLo[4], bHi[4];
      #pragma unroll
      for (int g = 0; g < 4; ++g){
        bLo[g] = MFMA16(a1[0], B2i[g][0], zacc);
        bHi[g] = MFMA16(a1[2], B2i[g][2], zacc);
      }
      #pragma unroll
      for (int g = 0; g < 4; ++g){
        bLo[g] = MFMA16(a1[1], B2i[g][1], bLo[g]);
        bHi[g] = MFMA16(a1[3], B2i[g][3], bHi[g]);
      }
      #pragma unroll
      for (int g = 0; g < 4; ++g){
        bLo[g] = MFMA16(a2[0], B2h[g][0], bLo[g]);
        bHi[g] = MFMA16(a2[1], B2h[g][1], bHi[g]);
      }
      if (l < 16){
        float g4[4];
        #pragma unroll
        for (int g = 0; g < 4; ++g)
          g4[g] = bLo[g][0] + bHi[g][0] + biasB[g];
        c2 = sigmoid_f(g4[1]) * c2 + sigmoid_f(g4[0]) * tanh_f(g4[2]);
        float h = sigmoid_f(g4[3]) * tanh_f(c2);
        H2[wa2][cellB] = (_Float16)h;
      }
    }
    __syncthreads();
  }

  // ---- epilogue: L2 step TB-1 -> output.
  //      h1(1023) in H1[1]; h2(1022) in H2[0] (slot = m&1) ----
  if (w < 4){
    const f16x8* pA1 = (const f16x8*)&H1[1][0];
    f16x8 a1[4];
    #pragma unroll
    for (int k = 0; k < 4; ++k) a1[k] = pA1[4*k + quad];
    const f16x8* pA2 = (const f16x8*)&H2[0][0];
    f16x8 a2[2];
    #pragma unroll
    for (int k = 0; k < 2; ++k) a2[k] = pA2[4*k + quad];
    f32x4 bLo[4], bHi[4];
    #pragma unroll
    for (int g = 0; g < 4; ++g){
      bLo[g] = MFMA16(a1[0], B2i[g][0], zacc);
      bHi[g] = MFMA16(a1[2], B2i[g][2], zacc);
    }
    #pragma unroll
    for (int g = 0; g < 4; ++g){
      bLo[g] = MFMA16(a1[1], B2i[g][1], bLo[g]);
      bHi[g] = MFMA16(a1[3], B2i[g][3], bHi[g]);
    }
    #pragma unroll
    for (int g = 0; g < 4; ++g){
      bLo[g] = MFMA16(a2[0], B2h[g][0], bLo[g]);
      bHi[g] = MFMA16(a2[1], B2h[g][1], bHi[g]);
    }
    if (l < 16){
      float g4[4];
      #pragma unroll
      for (int g = 0; g < 4; ++g)
        g4[g] = bLo[g][0] + bHi[g][0] + biasB[g];
      c2 = sigmoid_f(g4[1]) * c2 + sigmoid_f(g4[0]) * tanh_f(g4[2]);
      float h = sigmoid_f(g4[3]) * tanh_f(c2);
      out[b * EMB2 + cellB] = h;
    }
  }
}

extern "C" void kernel_launch(void* const* d_in, const int* in_sizes, int n_in,
                              void* d_out, int out_size, void* d_ws, size_t ws_size,
                              hipStream_t stream) {
  lstm2_kernel<<<dim3(128), dim3(512), 0, stream>>>(
      (const float*)d_in[0],   // x
      (const float*)d_in[1],   // w_ih1
      (const float*)d_in[2],   // w_hh1
      (const float*)d_in[3],   // b_ih1
      (const float*)d_in[4],   // b_hh1
      (const float*)d_in[5],   // w_ih2
      (const float*)d_in[6],   // w_hh2
      (const float*)d_in[7],   // b_ih2
      (const float*)d_in[8],   // b_hh2
      (float*)d_out);
}